// Round 3
// baseline (471.424 us; speedup 1.0000x reference)
//
#include <hip/hip_runtime.h>
#include <stdint.h>

// ---------------------------------------------------------------------------
// TransformerBlock: RoPE -> QKV -> sliding-window attention (WIN=256) ->
// out_proj -> +res LN1 -> FFN(GELU tanh-form) -> +res LN2.
// B=8, S=1024, E=1024, H=16, HD=64. All GEMMs via bf16 MFMA 16x16x32.
// Big GEMMs (QKV, FF1): 256x256 8-phase counted-vmcnt template, vmcnt(6).
// FF2 (N=1024, K=4096): same template, split-K=2 -> fp32 partials (P0/P1),
//   fused into LN2 (x1 + P0 + P1 + bias -> LN). Grid 256 = 1 block/CU.
// out_proj: 128x128 tile, BK=64, XOR-swizzled LDS.
// ---------------------------------------------------------------------------

#define B_ 8
#define S_ 1024
#define E_ 1024
#define H_ 16
#define HD_ 64
#define WIN_ 256
#define QKV_ 3072   // merged QKV row stride

typedef __attribute__((ext_vector_type(8))) short short8;
typedef __attribute__((ext_vector_type(4))) float f32x4;
typedef __attribute__((ext_vector_type(4))) unsigned short us4;
typedef unsigned short ushort_t;

__device__ __forceinline__ ushort_t f2b(float f) {
  unsigned int u = __builtin_bit_cast(unsigned int, f);
  u = (u + 0x7fffu + ((u >> 16) & 1u)) >> 16;
  return (ushort_t)u;
}

__device__ __forceinline__ ushort_t f2b_trunc(float f) {
  return (ushort_t)(__builtin_bit_cast(unsigned int, f) >> 16);
}

__device__ __forceinline__ float b2f(ushort_t u) {
  return __builtin_bit_cast(float, ((unsigned int)u) << 16);
}

__device__ __forceinline__ float fast_exp2(float x) {
#if __has_builtin(__builtin_amdgcn_exp2f)
  return __builtin_amdgcn_exp2f(x);
#else
  return exp2f(x);
#endif
}

__device__ __forceinline__ float fast_rcp(float x) {
#if __has_builtin(__builtin_amdgcn_rcpf)
  return __builtin_amdgcn_rcpf(x);
#else
  return 1.f / x;
#endif
}

__device__ __forceinline__ void gld_lds16(const void* g, void* l) {
  __builtin_amdgcn_global_load_lds((const __attribute__((address_space(1))) void*)g,
                                   (__attribute__((address_space(3))) void*)l, 16, 0, 0);
}

// ---------------------------------------------------------------------------
// All four weight casts in one launch.
// ---------------------------------------------------------------------------
__global__ __launch_bounds__(256) void cast4_kernel(const float* __restrict__ i0,
                                                    const float* __restrict__ i1,
                                                    const float* __restrict__ i2,
                                                    const float* __restrict__ i3,
                                                    ushort_t* __restrict__ o0,
                                                    ushort_t* __restrict__ o1,
                                                    ushort_t* __restrict__ o2,
                                                    ushort_t* __restrict__ o3) {
  int i = blockIdx.x * 256 + threadIdx.x;
  const float* in;
  ushort_t* out;
  int j;
  if (i < 786432)       { in = i0; out = o0; j = i; }
  else if (i < 1048576) { in = i1; out = o1; j = i - 786432; }
  else if (i < 2097152) { in = i2; out = o2; j = i - 1048576; }
  else                  { in = i3; out = o3; j = i - 2097152; }
  float4 v = ((const float4*)in)[j];
  us4 o;
  o.x = f2b(v.x); o.y = f2b(v.y); o.z = f2b(v.z); o.w = f2b(v.w);
  ((us4*)out)[j] = o;
}

// ---------------------------------------------------------------------------
// RoPE on raw input; emits roped (bf16) and plain x (bf16) for the V proj.
// ---------------------------------------------------------------------------
__global__ __launch_bounds__(256) void rope_kernel(const float* __restrict__ x,
                                                   ushort_t* __restrict__ roped,
                                                   ushort_t* __restrict__ xbf) {
  int idx = blockIdx.x * 256 + threadIdx.x;   // B*S*H*32 = 4,194,304
  int d = idx & 31;
  int h = (idx >> 5) & 15;
  int s = (idx >> 9) & 1023;
  int b = idx >> 19;
  size_t base = ((size_t)(b * S_ + s)) * E_ + h * HD_ + d;
  float x0 = x[base], x1 = x[base + 32];
  float freq = exp2f(-(float)d * 0.41524101186092029f);
  float th = (float)s * freq;
  float sn, cs;
  sincosf(th, &sn, &cs);
  roped[base]      = f2b(x0 * cs - x1 * sn);
  roped[base + 32] = f2b(x1 * cs + x0 * sn);
  xbf[base]      = f2b(x0);
  xbf[base + 32] = f2b(x1);
}

// ---------------------------------------------------------------------------
// 128x128 GEMM (kept for out_proj, N=1024 K=1024).
// ---------------------------------------------------------------------------
template <int MODE>
__global__ __launch_bounds__(256) void gemm_bt(const ushort_t* __restrict__ A,
                                               const ushort_t* __restrict__ A2,
                                               int nsplit,
                                               const ushort_t* __restrict__ Bm,
                                               const float* __restrict__ bias,
                                               ushort_t* __restrict__ C,
                                               int N, int K) {
  __shared__ ushort_t sA[128 * 64];   // 16 KB
  __shared__ ushort_t sB[128 * 64];   // 16 KB
  const int tid = threadIdx.x;
  const int lane = tid & 63;
  const int wave = tid >> 6;
  const int quad = lane >> 4;
  const int lq = lane & 15;
  const int wm = (wave & 1) * 64;
  const int wn = (wave >> 1) * 64;
  const size_t bm = (size_t)blockIdx.x * 128;
  const size_t bn = (size_t)blockIdx.y * 128;
  const ushort_t* Asel = (bn >= (size_t)nsplit) ? A2 : A;

  f32x4 acc[4][4] = {};

  const int srow = lane >> 3;                       // row within 8-row group
  const int skc = ((lane & 7) ^ (lane >> 3)) * 8;   // logical k-chunk offset

  for (int k0 = 0; k0 < K; k0 += 64) {
#pragma unroll
    for (int i = 0; i < 4; i++) {
      const int r0 = wave * 32 + i * 8;
      gld_lds16(Asel + (bm + r0 + srow) * K + k0 + skc, &sA[r0 * 64]);
      gld_lds16(Bm + (bn + r0 + srow) * K + k0 + skc, &sB[r0 * 64]);
    }
    __syncthreads();

#pragma unroll
    for (int kk = 0; kk < 2; kk++) {
      const int csw = (((kk * 4) + quad) ^ (lq & 7)) * 8;   // phys chunk offset
      short8 av[4], bv[4];
#pragma unroll
      for (int mt = 0; mt < 4; mt++)
        av[mt] = *(const short8*)&sA[(wm + mt * 16 + lq) * 64 + csw];
#pragma unroll
      for (int nt = 0; nt < 4; nt++)
        bv[nt] = *(const short8*)&sB[(wn + nt * 16 + lq) * 64 + csw];
#pragma unroll
      for (int mt = 0; mt < 4; mt++)
#pragma unroll
        for (int nt = 0; nt < 4; nt++)
          acc[mt][nt] = __builtin_amdgcn_mfma_f32_16x16x32_bf16(av[mt], bv[nt], acc[mt][nt], 0, 0, 0);
    }
    __syncthreads();
  }

#pragma unroll
  for (int mt = 0; mt < 4; mt++) {
#pragma unroll
    for (int nt = 0; nt < 4; nt++) {
      size_t row = bm + wm + mt * 16 + quad * 4;
      size_t col = bn + wn + nt * 16 + lq;
      float bc = bias[col];
#pragma unroll
      for (int r = 0; r < 4; r++) {
        float v = acc[mt][nt][r] + bc;
        if (MODE == 1) {
          float y = 0.7978845608028654f * (v + 0.044715f * v * v * v);
          float t = fast_exp2(y * 2.8853900817779268f);
          v = v * (t * fast_rcp(1.f + t));
        }
        C[(row + r) * N + col] = f2b(v);
      }
    }
  }
}

// ---------------------------------------------------------------------------
// 256x256 8-phase GEMM (T2 swizzle + T3/T4 counted vmcnt + T5 setprio).
// 8 waves (2M x 4N), BK=64, LDS 128 KiB = 2 K-tile double buffer, each
// operand split into two 128x64 half-tile slots.
// Quadrant order (Mh,Nh): (0,0)(0,1)(1,1)(1,0). Slot read phases per tile:
//   A0: ph1 | B1: ph2 | A1: ph3 | B0: ph1 + ph4 (re-read).
// Steady-state stage schedule (iteration computing tiles t [buf0], t+1 [buf1]):
//   ph1: B0(t+1)->buf1   ph2: A0(t+2)->buf0   ph3: B1(t+2)->buf0
//   ph4: A1(t+2)->buf0 + vmcnt(6)            [confirms tile t+1 landed]
//   ph5: B0(t+2)->buf0   ph6: A0(t+3)->buf1   ph7: B1(t+3)->buf1
//   ph8: A1(t+3)->buf1 + vmcnt(6)            [confirms tile t+2 landed]
// Peeled final iteration stages only B0(NT-1) at ph1, drains vmcnt(0) at ph4.
// MODE: 0 = bf16 out + bias; 1 = bf16 + bias + GELU;
//       2 = split-K fp32 partial, NO bias; ks=0 writes C, ks=1 writes 'bias'
//           (reinterpreted as float* P1 base — bias is unused in MODE 2).
// Klen = per-split K length (loop bound); K = row stride; nbn = # N-tiles.
// ---------------------------------------------------------------------------
#define FENCE asm volatile("" ::: "memory")
#define VM6 asm volatile("s_waitcnt vmcnt(6)" ::: "memory")
#define VM0 asm volatile("s_waitcnt vmcnt(0)" ::: "memory")
#define NOPW ((void)0)

#define STAGE_A(bufc, half, kb)                                               \
  { gld_lds16(aSrc + (size_t)((half) * 128) * K + (kb),                       \
              &lds[16384 * (bufc) + 8192 * (half) + wave * 512]);             \
    gld_lds16(aSrc + (size_t)((half) * 128 + 64) * K + (kb),                  \
              &lds[16384 * (bufc) + 8192 * (half) + 4096 + wave * 512]); }

#define STAGE_B(bufc, half, kb)                                               \
  { gld_lds16(bSrc + (size_t)((half) * 128) * K + (kb),                       \
              &lds[32768 + 16384 * (bufc) + 8192 * (half) + wave * 512]);     \
    gld_lds16(bSrc + (size_t)((half) * 128 + 64) * K + (kb),                  \
              &lds[32768 + 16384 * (bufc) + 8192 * (half) + 4096 + wave * 512]); }

#define PHASE(qq, bufc, doA, doB, STAGE_STMT, WAIT_STMT)                      \
  {                                                                           \
    if (doA) {                                                                \
      const int abase = 16384 * (bufc) + 8192 * ((qq) >> 1);                  \
      _Pragma("unroll") for (int mf = 0; mf < 4; mf++) {                      \
        const int ra = wm * 64 + mf * 16 + lq;                                \
        _Pragma("unroll") for (int k2 = 0; k2 < 2; k2++)                      \
          av[mf][k2] = *(const short8*)&lds[abase + ra * 64 +                 \
                                            (((k2 * 4 + quad) ^ (lq & 7)) << 3)]; \
      }                                                                       \
    }                                                                         \
    if (doB) {                                                                \
      const int bbase = 32768 + 16384 * (bufc) +                              \
                        8192 * ((((qq) == 1) || ((qq) == 2)) ? 1 : 0);        \
      _Pragma("unroll") for (int nf = 0; nf < 2; nf++) {                      \
        const int rb = wn * 32 + nf * 16 + lq;                                \
        _Pragma("unroll") for (int k2 = 0; k2 < 2; k2++)                      \
          bv[nf][k2] = *(const short8*)&lds[bbase + rb * 64 +                 \
                                            (((k2 * 4 + quad) ^ (lq & 7)) << 3)]; \
      }                                                                       \
    }                                                                         \
    STAGE_STMT;                                                               \
    FENCE; __builtin_amdgcn_s_barrier(); FENCE;                               \
    __builtin_amdgcn_s_setprio(1);                                            \
    _Pragma("unroll") for (int k2 = 0; k2 < 2; k2++)                          \
      _Pragma("unroll") for (int mf = 0; mf < 4; mf++)                        \
        _Pragma("unroll") for (int nf = 0; nf < 2; nf++)                      \
          acc[qq][mf][nf] = __builtin_amdgcn_mfma_f32_16x16x32_bf16(          \
              av[mf][k2], bv[nf][k2], acc[qq][mf][nf], 0, 0, 0);              \
    __builtin_amdgcn_s_setprio(0);                                            \
    WAIT_STMT;                                                                \
    FENCE; __builtin_amdgcn_s_barrier(); FENCE;                               \
  }

template <int MODE>
__global__ __launch_bounds__(512, 2) void gemm256(const ushort_t* __restrict__ A,
                                                  const ushort_t* __restrict__ A2,
                                                  int nsplit,
                                                  const ushort_t* __restrict__ Bm,
                                                  const float* __restrict__ bias,
                                                  ushort_t* __restrict__ C,
                                                  int N, int Klen, int K,
                                                  int nbx, int nbn) {
  __shared__ ushort_t lds[65536];   // 128 KiB: A slots [0,32768) B slots [32768,65536)
  const int tid = threadIdx.x;
  const int lane = tid & 63, wave = tid >> 6;
  const int quad = lane >> 4, lq = lane & 15;
  const int wm = wave >> 2, wn = wave & 3;

  // XCD-aware block swizzle (grids here are multiples of 8)
  const int nwg = gridDim.x;
  const int id = blockIdx.x;
  const int wg = (nwg & 7) ? id : ((id & 7) * (nwg >> 3) + (id >> 3));
  const int bx = wg % nbx;
  const int byt = wg / nbx;
  const int bny = byt % nbn;           // N-tile index
  const int ks = byt / nbn;            // K-split index
  const size_t bm = (size_t)bx * 256, bn = (size_t)bny * 256;
  const ushort_t* Asel = ((int)bn >= nsplit) ? A2 : A;
  const size_t koff = (size_t)ks * Klen;

  const int srow = lane >> 3;
  const int scol = ((lane & 7) ^ srow) << 3;   // pre-swizzled k-chunk
  const ushort_t* aSrc = Asel + (bm + wave * 8 + srow) * (size_t)K + koff + scol;
  const ushort_t* bSrc = Bm + (bn + wave * 8 + srow) * (size_t)K + koff + scol;

  f32x4 acc[4][4][2] = {};
  short8 av[4][2], bv[2][2];

  // prologue: tile0 complete (8 loads) + tile1 A0,B1,A1 (6 loads); vmcnt(6)
  // confirms tile0, leaves tile1's 3 staged half-tiles in flight.
  STAGE_A(0, 0, 0); STAGE_A(0, 1, 0); STAGE_B(0, 0, 0); STAGE_B(0, 1, 0);
  STAGE_A(1, 0, 64); STAGE_B(1, 1, 64); STAGE_A(1, 1, 64);
  VM6;
  FENCE; __builtin_amdgcn_s_barrier(); FENCE;

  const int NT = Klen >> 6;   // K-tiles of 64 (must be even, >= 4)
#pragma unroll 1
  for (int i = 0; i < (NT >> 1) - 1; i++) {
    const int kb0 = i << 7;   // tile t = 2i
    PHASE(0, 0, 1, 1, STAGE_B(1, 0, kb0 + 64), NOPW);    // B0(t+1)
    PHASE(1, 0, 0, 1, STAGE_A(0, 0, kb0 + 128), NOPW);   // A0(t+2)
    PHASE(2, 0, 1, 0, STAGE_B(0, 1, kb0 + 128), NOPW);   // B1(t+2)
    PHASE(3, 0, 0, 1, STAGE_A(0, 1, kb0 + 128), VM6);    // A1(t+2); t+1 landed
    PHASE(0, 1, 1, 1, STAGE_B(0, 0, kb0 + 128), NOPW);   // B0(t+2)
    PHASE(1, 1, 0, 1, STAGE_A(1, 0, kb0 + 192), NOPW);   // A0(t+3)
    PHASE(2, 1, 1, 0, STAGE_B(1, 1, kb0 + 192), NOPW);   // B1(t+3)
    PHASE(3, 1, 0, 1, STAGE_A(1, 1, kb0 + 192), VM6);    // A1(t+3); t+2 landed
  }
  {
    // peeled final iteration (tiles NT-2 [buf0], NT-1 [buf1]): only B0(NT-1)
    // remains to stage; drain all loads at ph4 before buf1 is read.
    const int kb0 = (NT - 2) << 6;
    PHASE(0, 0, 1, 1, STAGE_B(1, 0, kb0 + 64), NOPW);
    PHASE(1, 0, 0, 1, NOPW, NOPW);
    PHASE(2, 0, 1, 0, NOPW, NOPW);
    PHASE(3, 0, 0, 1, NOPW, VM0);
    PHASE(0, 1, 1, 1, NOPW, NOPW);
    PHASE(1, 1, 0, 1, NOPW, NOPW);
    PHASE(2, 1, 1, 0, NOPW, NOPW);
    PHASE(3, 1, 0, 1, NOPW, NOPW);
  }

  // epilogue: MODE 0/1 -> bias (+GELU), bf16; MODE 2 -> fp32 partial, base
  // selected by ks (C for ks=0, 'bias' reinterpreted as P1 base for ks=1).
  float* Pf = (MODE == 2) ? (ks ? (float*)bias : (float*)C) : nullptr;
#pragma unroll
  for (int q = 0; q < 4; q++) {
    const int Mh = q >> 1;
    const int Nh = (q == 1 || q == 2) ? 1 : 0;
#pragma unroll
    for (int mf = 0; mf < 4; mf++) {
#pragma unroll
      for (int nf = 0; nf < 2; nf++) {
        size_t row = bm + Mh * 128 + wm * 64 + mf * 16 + quad * 4;
        size_t col = bn + Nh * 128 + wn * 32 + nf * 16 + lq;
        float bc = (MODE == 2) ? 0.f : bias[col];
#pragma unroll
        for (int r = 0; r < 4; r++) {
          float v = acc[q][mf][nf][r] + bc;
          if (MODE == 1) {
            float y = 0.7978845608028654f * (v + 0.044715f * v * v * v);
            float t = fast_exp2(y * 2.8853900817779268f);
            v = v * (t * fast_rcp(1.f + t));
          }
          if (MODE == 2) {
            Pf[(row + r) * (size_t)N + col] = v;
          } else {
            C[(row + r) * N + col] = f2b(v);
          }
        }
      }
    }
  }
}

// ---------------------------------------------------------------------------
// V transpose: qkv[b*S+s][2048 + h*64 + d] -> vt[((b*16+h)*64+d)*S + s]
// ---------------------------------------------------------------------------
__global__ __launch_bounds__(256) void vtrans_kernel(const ushort_t* __restrict__ qkv,
                                                     ushort_t* __restrict__ vt) {
  __shared__ ushort_t tb[64 * 65];
  int bh = blockIdx.x >> 4;    // 0..127
  int st = blockIdx.x & 15;
  int b = bh >> 4, h = bh & 15;
  int s0 = st * 64;
  int tid = threadIdx.x;
  int c = tid & 63, rbase = tid >> 6;
#pragma unroll
  for (int rep = 0; rep < 16; rep++) {
    int i = rep * 4 + rbase;  // s-local
    tb[c * 65 + i] = qkv[(size_t)(b * S_ + s0 + i) * QKV_ + 2048 + h * HD_ + c];
  }
  __syncthreads();
#pragma unroll
  for (int rep = 0; rep < 16; rep++) {
    int d = rep * 4 + rbase;  // head-dim
    vt[(size_t)((b * H_ + h) * HD_ + d) * S_ + s0 + c] = tb[d * 65 + c];
  }
}

// ---------------------------------------------------------------------------
// Sliding-window flash attention: block-cooperative LDS staging.
// ---------------------------------------------------------------------------
#define SC_ 0.18033688011112042f  // 0.125 * log2(e)

__global__ __launch_bounds__(256) void attn_kernel(const ushort_t* __restrict__ qkv,
                                                   const ushort_t* __restrict__ vt,
                                                   ushort_t* __restrict__ ctx) {
  __shared__ ushort_t sK[2][32 * 64];   // [key][dim]
  __shared__ ushort_t sV[2][64 * 32];   // [dim][key]
  __shared__ ushort_t sP[4][16 * 36];   // per-wave P tile
  const int tid = threadIdx.x;
  const int lane = tid & 63, wave = tid >> 6;
  const int quad = lane >> 4, lq = lane & 15;
  int gid = ((blockIdx.x & 7) << 8) | (blockIdx.x >> 3);
  int qs = gid & 15;          // 64-query super-tile
  int h = (gid >> 4) & 15;
  int b = gid >> 8;
  int qs64 = qs * 64;
  int q0 = qs64 + wave * 16;

  const size_t qoff = (size_t)(b * S_ + q0 + lq) * QKV_ + h * HD_;
  short8 a0 = *(const short8*)&qkv[qoff + quad * 8];
  short8 a1 = *(const short8*)&qkv[qoff + 32 + quad * 8];

  f32x4 o[4] = {};
  float rs[4] = {0.f, 0.f, 0.f, 0.f};

  int start = qs64 - WIN_; if (start < 0) start = 0;
  int end = qs64 + 64 + WIN_; if (end > S_) end = S_;
  const int wlo = q0 - WIN_;
  const int whi = q0 + 16 + WIN_;

  const ushort_t* kg = qkv + (size_t)(b * S_) * QKV_ + 1024 + h * HD_;
  const ushort_t* vg = vt + (size_t)((b * H_ + h) * HD_) * S_;

  const int krow = lane >> 3;
  const int kchg = ((lane & 7) ^ krow) << 3;
  const int vrow = lane >> 2;
  const int vchg = ((lane & 3) ^ ((lane >> 3) & 3)) << 3;

  gld_lds16(kg + (size_t)(start + wave * 8 + krow) * QKV_ + kchg, &sK[0][wave * 512]);
  gld_lds16(vg + (size_t)(wave * 16 + vrow) * S_ + start + vchg, &sV[0][wave * 512]);

  const int nch = (end - start) >> 5;
  int buf = 0;
  for (int c = 0; c < nch; c++) {
    __syncthreads();
    int kb = start + c * 32;
    if (c + 1 < nch) {
      int nkb = kb + 32;
      gld_lds16(kg + (size_t)(nkb + wave * 8 + krow) * QKV_ + kchg, &sK[buf ^ 1][wave * 512]);
      gld_lds16(vg + (size_t)(wave * 16 + vrow) * S_ + nkb + vchg, &sV[buf ^ 1][wave * 512]);
    }
    if (kb < whi && kb + 32 > wlo) {
      f32x4 s[2];
#pragma unroll
      for (int t = 0; t < 2; t++) {
        const ushort_t* kr = &sK[buf][(t * 16 + lq) * 64];
        short8 b0 = *(const short8*)&kr[((quad ^ (lq & 7)) << 3)];
        short8 b1 = *(const short8*)&kr[(((4 + quad) ^ (lq & 7)) << 3)];
        f32x4 z = {};
        z = __builtin_amdgcn_mfma_f32_16x16x32_bf16(a0, b0, z, 0, 0, 0);
        z = __builtin_amdgcn_mfma_f32_16x16x32_bf16(a1, b1, z, 0, 0, 0);
        s[t] = z;
      }
      float p[2][4];
      const bool full = (kb >= q0 - 241) && (kb <= q0 + 225);
      if (full) {
#pragma unroll
        for (int t = 0; t < 2; t++)
#pragma unroll
          for (int r = 0; r < 4; r++) p[t][r] = fast_exp2(s[t][r] * SC_);
      } else {
#pragma unroll
        for (int t = 0; t < 2; t++) {
          int ki = kb + t * 16 + lq;
#pragma unroll
          for (int r = 0; r < 4; r++) {
            int dd = q0 + quad * 4 + r - ki;
            bool allowed = (dd <= WIN_) && (dd >= -WIN_);
            p[t][r] = allowed ? fast_exp2(s[t][r] * SC_) : 0.f;
          }
        }
      }
#pragma unroll
      for (int r = 0; r < 4; r++) rs[r] += p[0][r] + p[1][r];

#pragma unroll
      for (int t = 0; t < 2; t++)
#pragma unroll
        for (int r = 0; r < 4; r++)
          sP[wave][(quad * 4 + r) * 36 + t * 16 + lq] = f2b_trunc(p[t][r]);
      asm volatile("s_waitcnt lgkmcnt(0)" ::: "memory");
      short8 ap = *(const short8*)&sP[wave][lq * 36 + quad * 8];

#pragma unroll
      for (int nt = 0; nt < 4; nt++) {
        short8 bvf = *(const short8*)&sV[buf][(nt * 16 + lq) * 32 +
                                             ((quad ^ ((lq >> 1) & 3)) << 3)];
        o[nt] = __builtin_amdgcn_mfma_f32_16x16x32_bf16(ap, bvf, o[nt], 0, 0, 0);
      }
    }
    buf ^= 1;
  }

  float inv[4];
#pragma unroll
  for (int r = 0; r < 4; r++) {
    float v = rs[r];
    v += __shfl_xor(v, 1);
    v += __shfl_xor(v, 2);
    v += __shfl_xor(v, 4);
    v += __shfl_xor(v, 8);
    inv[r] = 1.f / v;
  }

#pragma unroll
  for (int nt = 0; nt < 4; nt++)
#pragma unroll
    for (int r = 0; r < 4; r++) {
      int row = q0 + quad * 4 + r;
      int col = h * HD_ + nt * 16 + lq;
      ctx[(size_t)(b * S_ + row) * E_ + col] = f2b(o[nt][r] * inv[r]);
    }
}

// ---------------------------------------------------------------------------
// y = A + Bv (residual, Bv bf16); out = LN(y)*g + b. outf fp32; outb bf16 opt.
// ---------------------------------------------------------------------------
__global__ __launch_bounds__(256) void ln_res_kernel(const float* __restrict__ A,
                                                     const ushort_t* __restrict__ Bv,
                                                     const float* __restrict__ g,
                                                     const float* __restrict__ be,
                                                     float* __restrict__ outf,
                                                     ushort_t* __restrict__ outb) {
  const int row = blockIdx.x;
  const int tid = threadIdx.x;
  const size_t base = (size_t)row * 1024;
  float4 a4 = ((const float4*)(A + base))[tid];
  us4 b4 = ((const us4*)(Bv + base))[tid];
  float v[4];
  v[0] = a4.x + b2f(b4.x);
  v[1] = a4.y + b2f(b4.y);
  v[2] = a4.z + b2f(b4.z);
  v[3] = a4.w + b2f(b4.w);
  float s = v[0] + v[1] + v[2] + v[3];
  float sq = v[0] * v[0] + v[1] * v[1] + v[2] * v[2] + v[3] * v[3];
#pragma unroll
  for (int off = 32; off; off >>= 1) {
    s += __shfl_xor(s, off);
    sq += __shfl_xor(sq, off);
  }
  __shared__ float ls[4], lsq[4];
  int wave = tid >> 6, lane = tid & 63;
  if (lane == 0) { ls[wave] = s; lsq[wave] = sq; }
  __syncthreads();
  s = ls[0] + ls[1] + ls[2] + ls[3];
  sq = lsq[0] + lsq[1] + lsq[2] + lsq[3];
  float mean = s * (1.f / 1024.f);
  float var = sq * (1.f / 1024.f) - mean * mean;
  float rstd = rsqrtf(var + 1e-5f);
  float4 g4 = ((const float4*)g)[tid];
  float4 e4 = ((const float4*)be)[tid];
  float o0 = (v[0] - mean) * rstd * g4.x + e4.x;
  float o1 = (v[1] - mean) * rstd * g4.y + e4.y;
  float o2 = (v[2] - mean) * rstd * g4.z + e4.z;
  float o3 = (v[3] - mean) * rstd * g4.w + e4.w;
  float4 of = {o0, o1, o2, o3};
  ((float4*)(outf + base))[tid] = of;
  if (outb) {
    us4 ob;
    ob.x = f2b(o0); ob.y = f2b(o1); ob.z = f2b(o2); ob.w = f2b(o3);
    ((us4*)(outb + base))[tid] = ob;
  }
}

// ---------------------------------------------------------------------------
// Split-K fused LN2: y = x1 + P0 + P1 + bias (all fp32); out = LN(y)*g + b.
// ---------------------------------------------------------------------------
__global__ __launch_bounds__(256) void ln_res2_kernel(const float* __restrict__ A,
                                                      const float* __restrict__ P0,
                                                      const float* __restrict__ P1,
                                                      const float* __restrict__ bias,
                                                      const float* __restrict__ g,
                                                      const float* __restrict__ be,
                                                      float* __restrict__ outf) {
  const int row = blockIdx.x;
  const int tid = threadIdx.x;
  const size_t base = (size_t)row * 1024;
  float4 a4 = ((const float4*)(A + base))[tid];
  float4 p04 = ((const float4*)(P0 + base))[tid];
  float4 p14 = ((const float4*)(P1 + base))[tid];
  float4 bi4 = ((const float4*)bias)[tid];
  float v[4];
  v[0] = a4.x + p04.x + p14.x + bi4.x;
  v[1] = a4.y + p04.y + p14.y + bi4.y;
  v[2] = a4.z + p04.z + p14.z + bi4.z;
  v[3] = a4.w + p04.w + p14.w + bi4.w;
  float s = v[0] + v[1] + v[2] + v[3];
  float sq = v[0] * v[0] + v[1] * v[1] + v[2] * v[2] + v[3] * v[3];
#pragma unroll
  for (int off = 32; off; off >>= 1) {
    s += __shfl_xor(s, off);
    sq += __shfl_xor(sq, off);
  }
  __shared__ float ls[4], lsq[4];
  int wave = tid >> 6, lane = tid & 63;
  if (lane == 0) { ls[wave] = s; lsq[wave] = sq; }
  __syncthreads();
  s = ls[0] + ls[1] + ls[2] + ls[3];
  sq = lsq[0] + lsq[1] + lsq[2] + lsq[3];
  float mean = s * (1.f / 1024.f);
  float var = sq * (1.f / 1024.f) - mean * mean;
  float rstd = rsqrtf(var + 1e-5f);
  float4 g4 = ((const float4*)g)[tid];
  float4 e4 = ((const float4*)be)[tid];
  float4 of;
  of.x = (v[0] - mean) * rstd * g4.x + e4.x;
  of.y = (v[1] - mean) * rstd * g4.y + e4.y;
  of.z = (v[2] - mean) * rstd * g4.z + e4.z;
  of.w = (v[3] - mean) * rstd * g4.w + e4.w;
  ((float4*)(outf + base))[tid] = of;
}

// ---------------------------------------------------------------------------
// Workspace layout (bytes), lifetime-overlapped. Budget 200 MiB.
// ---------------------------------------------------------------------------
#define O_XBF   ((size_t)0)            // x bf16; later x1 bf16; later P0 (32MB w/ roped)
#define O_ROPED ((size_t)16777216)     // roped bf16; later ctx bf16; later P0 tail
#define O_W_IN  ((size_t)33554432)     // in_proj_w bf16 [3072][1024]
#define O_W_OUT ((size_t)39845888)     // out_proj_w bf16 [1024][1024]
#define O_W1    ((size_t)41943040)     // w1 bf16 [4096][1024]
#define O_W2    ((size_t)50331648)     // w2 bf16 [1024][4096]
#define O_BIG   ((size_t)58720256)     // qkv bf16 [8192][3072]; then h; then ff1
#define O_VT    ((size_t)125829120)    // V^T bf16 [B,H,HD,S]
#define O_X1F   ((size_t)142606336)    // x1 fp32 [8192][1024]
#define O_P1    ((size_t)176160768)    // FF2 partial 1 fp32 [8192][1024] (ends at 200 MiB)

extern "C" void kernel_launch(void* const* d_in, const int* in_sizes, int n_in,
                              void* d_out, int out_size, void* d_ws, size_t ws_size,
                              hipStream_t stream) {
  const float* x          = (const float*)d_in[0];
  const float* in_proj_w  = (const float*)d_in[1];
  const float* in_proj_b  = (const float*)d_in[2];
  const float* out_proj_w = (const float*)d_in[3];
  const float* out_proj_b = (const float*)d_in[4];
  const float* ln1_g      = (const float*)d_in[5];
  const float* ln1_b      = (const float*)d_in[6];
  const float* w1         = (const float*)d_in[7];
  const float* b1         = (const float*)d_in[8];
  const float* w2         = (const float*)d_in[9];
  const float* b2         = (const float*)d_in[10];
  const float* ln2_g      = (const float*)d_in[11];
  const float* ln2_b      = (const float*)d_in[12];
  float* out = (float*)d_out;

  char* ws = (char*)d_ws;
  ushort_t* xbf     = (ushort_t*)(ws + O_XBF);
  ushort_t* roped   = (ushort_t*)(ws + O_ROPED);
  ushort_t* wbf_in  = (ushort_t*)(ws + O_W_IN);
  ushort_t* wbf_out = (ushort_t*)(ws + O_W_OUT);
  ushort_t* wbf_1   = (ushort_t*)(ws + O_W1);
  ushort_t* wbf_2   = (ushort_t*)(ws + O_W2);
  ushort_t* qkv_buf = (ushort_t*)(ws + O_BIG);
  ushort_t* vtb     = (ushort_t*)(ws + O_VT);
  ushort_t* ctx     = (ushort_t*)(ws + O_ROPED);  // reuse roped
  ushort_t* h_bf    = (ushort_t*)(ws + O_BIG);    // reuse qkv region
  float*    x1f     = (float*)(ws + O_X1F);
  ushort_t* x1bf    = (ushort_t*)(ws + O_XBF);    // reuse xbf
  ushort_t* ff1     = (ushort_t*)(ws + O_BIG);    // reuse h region
  float*    p0      = (float*)(ws + O_XBF);       // FF2 partial 0: [0,32MB)
  float*    p1      = (float*)(ws + O_P1);        // FF2 partial 1

  dim3 blk(256);
  dim3 blk512(512);
  const int NOSPLIT = 1 << 30;

  // 1) weight casts to bf16 (single launch)
  cast4_kernel<<<dim3(12288), blk, 0, stream>>>(in_proj_w, out_proj_w, w1, w2,
                                                wbf_in, wbf_out, wbf_1, wbf_2);

  // 2) RoPE (+ x cast)
  rope_kernel<<<dim3(16384), blk, 0, stream>>>(x, roped, xbf);

  // 3) QKV merged: cols 0..2047 use roped, cols 2048.. use xbf (N=3072)
  gemm256<0><<<dim3(384), blk512, 0, stream>>>(roped, xbf, 2048, wbf_in, in_proj_b,
                                               qkv_buf, QKV_, 1024, 1024, 32, 12);
  // 4) V transpose -> [B,H,HD,S]
  vtrans_kernel<<<dim3(2048), blk, 0, stream>>>(qkv_buf, vtb);

  // 5) windowed flash attention -> ctx bf16
  attn_kernel<<<dim3(2048), blk, 0, stream>>>(qkv_buf, vtb, ctx);

  // 6) h = ctx @ Wo^T + bo (bf16 out; N=1024 K=1024 -> 128^2 kernel)
  gemm_bt<0><<<dim3(64, 8), blk, 0, stream>>>(ctx, ctx, NOSPLIT, wbf_out, out_proj_b,
                                              h_bf, 1024, 1024);

  // 7) x1 = LN1(x + h) -> fp32 + bf16
  ln_res_kernel<<<dim3(8192), blk, 0, stream>>>(x, h_bf, ln1_g, ln1_b, x1f, x1bf);

  // 8) ff1 = gelu(x1 @ W1^T + b1) bf16 (N=4096), grid 512 = 2 full CU rounds
  gemm256<1><<<dim3(512), blk512, 0, stream>>>(x1bf, x1bf, NOSPLIT, wbf_1, b1,
                                               ff1, 4096, 1024, 1024, 32, 16);

  // 9) FF2 split-K=2 -> fp32 partials p0 (ks=0) / p1 (ks=1, via 'bias' slot).
  //    Grid 32 M-tiles x 4 N-tiles x 2 K-splits = 256 blocks = 1/CU.
  gemm256<2><<<dim3(256), blk512, 0, stream>>>(ff1, ff1, NOSPLIT, wbf_2,
                                               (const float*)p1, (ushort_t*)p0,
                                               1024, 2048, 4096, 32, 4);

  // 10) out = LN2(x1 + p0 + p1 + b2)
  ln_res2_kernel<<<dim3(8192), blk, 0, stream>>>(x1f, p0, p1, b2, ln2_g, ln2_b, out);
}

// Round 4
// 442.415 us; speedup vs baseline: 1.0656x; 1.0656x over previous
//
#include <hip/hip_runtime.h>
#include <stdint.h>

// ---------------------------------------------------------------------------
// TransformerBlock: RoPE -> QKV -> sliding-window attention (WIN=256) ->
// out_proj -> +res LN1 -> FFN(GELU tanh-form) -> +res LN2.
// B=8, S=1024, E=1024, H=16, HD=64. All GEMMs via bf16 MFMA 16x16x32.
// Big GEMMs (QKV, FF1): 256x256 8-phase counted-vmcnt template, vmcnt(6).
// FF2 (N=1024, K=4096): same template, split-K=2 -> fp32 partials (P0/P1),
//   fused into LN2 (x1 + P0 + P1 + bias -> LN). Grid 256 = 1 block/CU.
// XCD mapping: 2-D chunked swizzle (CX x CY rectangle per XCD) so each XCD's
//   L2 working set is ~6-12 MiB instead of streaming the whole A matrix
//   (was 17-33 MiB/XCD -> FETCH_SIZE 135-264 MB; predicted ~halved).
// out_proj: 128x128 tile, BK=64, XOR-swizzled LDS.
// ---------------------------------------------------------------------------

#define B_ 8
#define S_ 1024
#define E_ 1024
#define H_ 16
#define HD_ 64
#define WIN_ 256
#define QKV_ 3072   // merged QKV row stride

typedef __attribute__((ext_vector_type(8))) short short8;
typedef __attribute__((ext_vector_type(4))) float f32x4;
typedef __attribute__((ext_vector_type(4))) unsigned short us4;
typedef unsigned short ushort_t;

__device__ __forceinline__ ushort_t f2b(float f) {
  unsigned int u = __builtin_bit_cast(unsigned int, f);
  u = (u + 0x7fffu + ((u >> 16) & 1u)) >> 16;
  return (ushort_t)u;
}

__device__ __forceinline__ ushort_t f2b_trunc(float f) {
  return (ushort_t)(__builtin_bit_cast(unsigned int, f) >> 16);
}

__device__ __forceinline__ float b2f(ushort_t u) {
  return __builtin_bit_cast(float, ((unsigned int)u) << 16);
}

__device__ __forceinline__ float fast_exp2(float x) {
#if __has_builtin(__builtin_amdgcn_exp2f)
  return __builtin_amdgcn_exp2f(x);
#else
  return exp2f(x);
#endif
}

__device__ __forceinline__ float fast_rcp(float x) {
#if __has_builtin(__builtin_amdgcn_rcpf)
  return __builtin_amdgcn_rcpf(x);
#else
  return 1.f / x;
#endif
}

__device__ __forceinline__ void gld_lds16(const void* g, void* l) {
  __builtin_amdgcn_global_load_lds((const __attribute__((address_space(1))) void*)g,
                                   (__attribute__((address_space(3))) void*)l, 16, 0, 0);
}

// ---------------------------------------------------------------------------
// All four weight casts in one launch.
// ---------------------------------------------------------------------------
__global__ __launch_bounds__(256) void cast4_kernel(const float* __restrict__ i0,
                                                    const float* __restrict__ i1,
                                                    const float* __restrict__ i2,
                                                    const float* __restrict__ i3,
                                                    ushort_t* __restrict__ o0,
                                                    ushort_t* __restrict__ o1,
                                                    ushort_t* __restrict__ o2,
                                                    ushort_t* __restrict__ o3) {
  int i = blockIdx.x * 256 + threadIdx.x;
  const float* in;
  ushort_t* out;
  int j;
  if (i < 786432)       { in = i0; out = o0; j = i; }
  else if (i < 1048576) { in = i1; out = o1; j = i - 786432; }
  else if (i < 2097152) { in = i2; out = o2; j = i - 1048576; }
  else                  { in = i3; out = o3; j = i - 2097152; }
  float4 v = ((const float4*)in)[j];
  us4 o;
  o.x = f2b(v.x); o.y = f2b(v.y); o.z = f2b(v.z); o.w = f2b(v.w);
  ((us4*)out)[j] = o;
}

// ---------------------------------------------------------------------------
// RoPE on raw input; emits roped (bf16) and plain x (bf16) for the V proj.
// ---------------------------------------------------------------------------
__global__ __launch_bounds__(256) void rope_kernel(const float* __restrict__ x,
                                                   ushort_t* __restrict__ roped,
                                                   ushort_t* __restrict__ xbf) {
  int idx = blockIdx.x * 256 + threadIdx.x;   // B*S*H*32 = 4,194,304
  int d = idx & 31;
  int h = (idx >> 5) & 15;
  int s = (idx >> 9) & 1023;
  int b = idx >> 19;
  size_t base = ((size_t)(b * S_ + s)) * E_ + h * HD_ + d;
  float x0 = x[base], x1 = x[base + 32];
  float freq = exp2f(-(float)d * 0.41524101186092029f);
  float th = (float)s * freq;
  float sn, cs;
  sincosf(th, &sn, &cs);
  roped[base]      = f2b(x0 * cs - x1 * sn);
  roped[base + 32] = f2b(x1 * cs + x0 * sn);
  xbf[base]      = f2b(x0);
  xbf[base + 32] = f2b(x1);
}

// ---------------------------------------------------------------------------
// 128x128 GEMM (kept for out_proj, N=1024 K=1024).
// ---------------------------------------------------------------------------
template <int MODE>
__global__ __launch_bounds__(256) void gemm_bt(const ushort_t* __restrict__ A,
                                               const ushort_t* __restrict__ A2,
                                               int nsplit,
                                               const ushort_t* __restrict__ Bm,
                                               const float* __restrict__ bias,
                                               ushort_t* __restrict__ C,
                                               int N, int K) {
  __shared__ ushort_t sA[128 * 64];   // 16 KB
  __shared__ ushort_t sB[128 * 64];   // 16 KB
  const int tid = threadIdx.x;
  const int lane = tid & 63;
  const int wave = tid >> 6;
  const int quad = lane >> 4;
  const int lq = lane & 15;
  const int wm = (wave & 1) * 64;
  const int wn = (wave >> 1) * 64;
  const size_t bm = (size_t)blockIdx.x * 128;
  const size_t bn = (size_t)blockIdx.y * 128;
  const ushort_t* Asel = (bn >= (size_t)nsplit) ? A2 : A;

  f32x4 acc[4][4] = {};

  const int srow = lane >> 3;                       // row within 8-row group
  const int skc = ((lane & 7) ^ (lane >> 3)) * 8;   // logical k-chunk offset

  for (int k0 = 0; k0 < K; k0 += 64) {
#pragma unroll
    for (int i = 0; i < 4; i++) {
      const int r0 = wave * 32 + i * 8;
      gld_lds16(Asel + (bm + r0 + srow) * K + k0 + skc, &sA[r0 * 64]);
      gld_lds16(Bm + (bn + r0 + srow) * K + k0 + skc, &sB[r0 * 64]);
    }
    __syncthreads();

#pragma unroll
    for (int kk = 0; kk < 2; kk++) {
      const int csw = (((kk * 4) + quad) ^ (lq & 7)) * 8;   // phys chunk offset
      short8 av[4], bv[4];
#pragma unroll
      for (int mt = 0; mt < 4; mt++)
        av[mt] = *(const short8*)&sA[(wm + mt * 16 + lq) * 64 + csw];
#pragma unroll
      for (int nt = 0; nt < 4; nt++)
        bv[nt] = *(const short8*)&sB[(wn + nt * 16 + lq) * 64 + csw];
#pragma unroll
      for (int mt = 0; mt < 4; mt++)
#pragma unroll
        for (int nt = 0; nt < 4; nt++)
          acc[mt][nt] = __builtin_amdgcn_mfma_f32_16x16x32_bf16(av[mt], bv[nt], acc[mt][nt], 0, 0, 0);
    }
    __syncthreads();
  }

#pragma unroll
  for (int mt = 0; mt < 4; mt++) {
#pragma unroll
    for (int nt = 0; nt < 4; nt++) {
      size_t row = bm + wm + mt * 16 + quad * 4;
      size_t col = bn + wn + nt * 16 + lq;
      float bc = bias[col];
#pragma unroll
      for (int r = 0; r < 4; r++) {
        float v = acc[mt][nt][r] + bc;
        if (MODE == 1) {
          float y = 0.7978845608028654f * (v + 0.044715f * v * v * v);
          float t = fast_exp2(y * 2.8853900817779268f);
          v = v * (t * fast_rcp(1.f + t));
        }
        C[(row + r) * N + col] = f2b(v);
      }
    }
  }
}

// ---------------------------------------------------------------------------
// 256x256 8-phase GEMM (T2 swizzle + T3/T4 counted vmcnt + T5 setprio).
// 8 waves (2M x 4N), BK=64, LDS 128 KiB = 2 K-tile double buffer, each
// operand split into two 128x64 half-tile slots.
// Quadrant order (Mh,Nh): (0,0)(0,1)(1,1)(1,0). Slot read phases per tile:
//   A0: ph1 | B1: ph2 | A1: ph3 | B0: ph1 + ph4 (re-read).
// Steady-state stage schedule (iteration computing tiles t [buf0], t+1 [buf1]):
//   ph1: B0(t+1)->buf1   ph2: A0(t+2)->buf0   ph3: B1(t+2)->buf0
//   ph4: A1(t+2)->buf0 + vmcnt(6)            [confirms tile t+1 landed]
//   ph5: B0(t+2)->buf0   ph6: A0(t+3)->buf1   ph7: B1(t+3)->buf1
//   ph8: A1(t+3)->buf1 + vmcnt(6)            [confirms tile t+2 landed]
// Peeled final iteration stages only B0(NT-1) at ph1, drains vmcnt(0) at ph4.
// MODE: 0 = bf16 out + bias; 1 = bf16 + bias + GELU;
//       2 = split-K fp32 partial, NO bias; ks=0 writes C, ks=1 writes 'bias'
//           (reinterpreted as float* P1 base — bias is unused in MODE 2).
// Klen = per-split K length (loop bound); K = row stride; nbn = # N-tiles.
// XCD mapping: HW round-robins consecutive blockIdx across the 8 XCDs, so
// chunk = id&7 selects the XCD and within = id>>3 walks that XCD's chunk.
// Chunks are CX x CY tile rectangles (nbx/CX * nbyt/CY == 8, CX*CY == nwg/8)
// -> per-XCD L2 working set is A(CX tiles) + B(CY tiles) instead of the
// whole A panel. bx fastest within a chunk.
// ---------------------------------------------------------------------------
#define FENCE asm volatile("" ::: "memory")
#define VM6 asm volatile("s_waitcnt vmcnt(6)" ::: "memory")
#define VM0 asm volatile("s_waitcnt vmcnt(0)" ::: "memory")
#define NOPW ((void)0)

#define STAGE_A(bufc, half, kb)                                               \
  { gld_lds16(aSrc + (size_t)((half) * 128) * K + (kb),                       \
              &lds[16384 * (bufc) + 8192 * (half) + wave * 512]);             \
    gld_lds16(aSrc + (size_t)((half) * 128 + 64) * K + (kb),                  \
              &lds[16384 * (bufc) + 8192 * (half) + 4096 + wave * 512]); }

#define STAGE_B(bufc, half, kb)                                               \
  { gld_lds16(bSrc + (size_t)((half) * 128) * K + (kb),                       \
              &lds[32768 + 16384 * (bufc) + 8192 * (half) + wave * 512]);     \
    gld_lds16(bSrc + (size_t)((half) * 128 + 64) * K + (kb),                  \
              &lds[32768 + 16384 * (bufc) + 8192 * (half) + 4096 + wave * 512]); }

#define PHASE(qq, bufc, doA, doB, STAGE_STMT, WAIT_STMT)                      \
  {                                                                           \
    if (doA) {                                                                \
      const int abase = 16384 * (bufc) + 8192 * ((qq) >> 1);                  \
      _Pragma("unroll") for (int mf = 0; mf < 4; mf++) {                      \
        const int ra = wm * 64 + mf * 16 + lq;                                \
        _Pragma("unroll") for (int k2 = 0; k2 < 2; k2++)                      \
          av[mf][k2] = *(const short8*)&lds[abase + ra * 64 +                 \
                                            (((k2 * 4 + quad) ^ (lq & 7)) << 3)]; \
      }                                                                       \
    }                                                                         \
    if (doB) {                                                                \
      const int bbase = 32768 + 16384 * (bufc) +                              \
                        8192 * ((((qq) == 1) || ((qq) == 2)) ? 1 : 0);        \
      _Pragma("unroll") for (int nf = 0; nf < 2; nf++) {                      \
        const int rb = wn * 32 + nf * 16 + lq;                                \
        _Pragma("unroll") for (int k2 = 0; k2 < 2; k2++)                      \
          bv[nf][k2] = *(const short8*)&lds[bbase + rb * 64 +                 \
                                            (((k2 * 4 + quad) ^ (lq & 7)) << 3)]; \
      }                                                                       \
    }                                                                         \
    STAGE_STMT;                                                               \
    FENCE; __builtin_amdgcn_s_barrier(); FENCE;                               \
    __builtin_amdgcn_s_setprio(1);                                            \
    _Pragma("unroll") for (int k2 = 0; k2 < 2; k2++)                          \
      _Pragma("unroll") for (int mf = 0; mf < 4; mf++)                        \
        _Pragma("unroll") for (int nf = 0; nf < 2; nf++)                      \
          acc[qq][mf][nf] = __builtin_amdgcn_mfma_f32_16x16x32_bf16(          \
              av[mf][k2], bv[nf][k2], acc[qq][mf][nf], 0, 0, 0);              \
    __builtin_amdgcn_s_setprio(0);                                            \
    WAIT_STMT;                                                                \
    FENCE; __builtin_amdgcn_s_barrier(); FENCE;                               \
  }

template <int MODE>
__global__ __launch_bounds__(512, 2) void gemm256(const ushort_t* __restrict__ A,
                                                  const ushort_t* __restrict__ A2,
                                                  int nsplit,
                                                  const ushort_t* __restrict__ Bm,
                                                  const float* __restrict__ bias,
                                                  ushort_t* __restrict__ C,
                                                  int N, int Klen, int K,
                                                  int nbx, int nbn,
                                                  int CX, int CY) {
  __shared__ ushort_t lds[65536];   // 128 KiB: A slots [0,32768) B slots [32768,65536)
  const int tid = threadIdx.x;
  const int lane = tid & 63, wave = tid >> 6;
  const int quad = lane >> 4, lq = lane & 15;
  const int wm = wave >> 2, wn = wave & 3;

  // 2-D chunked XCD swizzle (requires nwg % 8 == 0, nbx % CX == 0,
  // CX*CY == nwg/8; all launches here satisfy this).
  const int nwg = gridDim.x;
  const int id = blockIdx.x;
  int bx, byt;
  if (nwg & 7) {
    bx = id % nbx; byt = id / nbx;
  } else {
    const int within = id >> 3;          // position inside this XCD's chunk
    const int chunk = id & 7;            // XCD index (HW round-robin)
    const int nchx = nbx / CX;           // chunks along bx
    bx = (chunk % nchx) * CX + (within % CX);
    byt = (chunk / nchx) * CY + (within / CX);
  }
  const int bny = byt % nbn;             // N-tile index
  const int ks = byt / nbn;              // K-split index
  const size_t bm = (size_t)bx * 256, bn = (size_t)bny * 256;
  const ushort_t* Asel = ((int)bn >= nsplit) ? A2 : A;
  const size_t koff = (size_t)ks * Klen;

  const int srow = lane >> 3;
  const int scol = ((lane & 7) ^ srow) << 3;   // pre-swizzled k-chunk
  const ushort_t* aSrc = Asel + (bm + wave * 8 + srow) * (size_t)K + koff + scol;
  const ushort_t* bSrc = Bm + (bn + wave * 8 + srow) * (size_t)K + koff + scol;

  f32x4 acc[4][4][2] = {};
  short8 av[4][2], bv[2][2];

  // prologue: tile0 complete (8 loads) + tile1 A0,B1,A1 (6 loads); vmcnt(6)
  // confirms tile0, leaves tile1's 3 staged half-tiles in flight.
  STAGE_A(0, 0, 0); STAGE_A(0, 1, 0); STAGE_B(0, 0, 0); STAGE_B(0, 1, 0);
  STAGE_A(1, 0, 64); STAGE_B(1, 1, 64); STAGE_A(1, 1, 64);
  VM6;
  FENCE; __builtin_amdgcn_s_barrier(); FENCE;

  const int NT = Klen >> 6;   // K-tiles of 64 (must be even, >= 4)
#pragma unroll 1
  for (int i = 0; i < (NT >> 1) - 1; i++) {
    const int kb0 = i << 7;   // tile t = 2i
    PHASE(0, 0, 1, 1, STAGE_B(1, 0, kb0 + 64), NOPW);    // B0(t+1)
    PHASE(1, 0, 0, 1, STAGE_A(0, 0, kb0 + 128), NOPW);   // A0(t+2)
    PHASE(2, 0, 1, 0, STAGE_B(0, 1, kb0 + 128), NOPW);   // B1(t+2)
    PHASE(3, 0, 0, 1, STAGE_A(0, 1, kb0 + 128), VM6);    // A1(t+2); t+1 landed
    PHASE(0, 1, 1, 1, STAGE_B(0, 0, kb0 + 128), NOPW);   // B0(t+2)
    PHASE(1, 1, 0, 1, STAGE_A(1, 0, kb0 + 192), NOPW);   // A0(t+3)
    PHASE(2, 1, 1, 0, STAGE_B(1, 1, kb0 + 192), NOPW);   // B1(t+3)
    PHASE(3, 1, 0, 1, STAGE_A(1, 1, kb0 + 192), VM6);    // A1(t+3); t+2 landed
  }
  {
    // peeled final iteration (tiles NT-2 [buf0], NT-1 [buf1]): only B0(NT-1)
    // remains to stage; drain all loads at ph4 before buf1 is read.
    const int kb0 = (NT - 2) << 6;
    PHASE(0, 0, 1, 1, STAGE_B(1, 0, kb0 + 64), NOPW);
    PHASE(1, 0, 0, 1, NOPW, NOPW);
    PHASE(2, 0, 1, 0, NOPW, NOPW);
    PHASE(3, 0, 0, 1, NOPW, VM0);
    PHASE(0, 1, 1, 1, NOPW, NOPW);
    PHASE(1, 1, 0, 1, NOPW, NOPW);
    PHASE(2, 1, 1, 0, NOPW, NOPW);
    PHASE(3, 1, 0, 1, NOPW, NOPW);
  }

  // epilogue: MODE 0/1 -> bias (+GELU), bf16; MODE 2 -> fp32 partial, base
  // selected by ks (C for ks=0, 'bias' reinterpreted as P1 base for ks=1).
  float* Pf = (MODE == 2) ? (ks ? (float*)bias : (float*)C) : nullptr;
#pragma unroll
  for (int q = 0; q < 4; q++) {
    const int Mh = q >> 1;
    const int Nh = (q == 1 || q == 2) ? 1 : 0;
#pragma unroll
    for (int mf = 0; mf < 4; mf++) {
#pragma unroll
      for (int nf = 0; nf < 2; nf++) {
        size_t row = bm + Mh * 128 + wm * 64 + mf * 16 + quad * 4;
        size_t col = bn + Nh * 128 + wn * 32 + nf * 16 + lq;
        float bc = (MODE == 2) ? 0.f : bias[col];
#pragma unroll
        for (int r = 0; r < 4; r++) {
          float v = acc[q][mf][nf][r] + bc;
          if (MODE == 1) {
            float y = 0.7978845608028654f * (v + 0.044715f * v * v * v);
            float t = fast_exp2(y * 2.8853900817779268f);
            v = v * (t * fast_rcp(1.f + t));
          }
          if (MODE == 2) {
            Pf[(row + r) * (size_t)N + col] = v;
          } else {
            C[(row + r) * N + col] = f2b(v);
          }
        }
      }
    }
  }
}

// ---------------------------------------------------------------------------
// V transpose: qkv[b*S+s][2048 + h*64 + d] -> vt[((b*16+h)*64+d)*S + s]
// ---------------------------------------------------------------------------
__global__ __launch_bounds__(256) void vtrans_kernel(const ushort_t* __restrict__ qkv,
                                                     ushort_t* __restrict__ vt) {
  __shared__ ushort_t tb[64 * 65];
  int bh = blockIdx.x >> 4;    // 0..127
  int st = blockIdx.x & 15;
  int b = bh >> 4, h = bh & 15;
  int s0 = st * 64;
  int tid = threadIdx.x;
  int c = tid & 63, rbase = tid >> 6;
#pragma unroll
  for (int rep = 0; rep < 16; rep++) {
    int i = rep * 4 + rbase;  // s-local
    tb[c * 65 + i] = qkv[(size_t)(b * S_ + s0 + i) * QKV_ + 2048 + h * HD_ + c];
  }
  __syncthreads();
#pragma unroll
  for (int rep = 0; rep < 16; rep++) {
    int d = rep * 4 + rbase;  // head-dim
    vt[(size_t)((b * H_ + h) * HD_ + d) * S_ + s0 + c] = tb[d * 65 + c];
  }
}

// ---------------------------------------------------------------------------
// Sliding-window flash attention: block-cooperative LDS staging.
// ---------------------------------------------------------------------------
#define SC_ 0.18033688011112042f  // 0.125 * log2(e)

__global__ __launch_bounds__(256) void attn_kernel(const ushort_t* __restrict__ qkv,
                                                   const ushort_t* __restrict__ vt,
                                                   ushort_t* __restrict__ ctx) {
  __shared__ ushort_t sK[2][32 * 64];   // [key][dim]
  __shared__ ushort_t sV[2][64 * 32];   // [dim][key]
  __shared__ ushort_t sP[4][16 * 36];   // per-wave P tile
  const int tid = threadIdx.x;
  const int lane = tid & 63, wave = tid >> 6;
  const int quad = lane >> 4, lq = lane & 15;
  int gid = ((blockIdx.x & 7) << 8) | (blockIdx.x >> 3);
  int qs = gid & 15;          // 64-query super-tile
  int h = (gid >> 4) & 15;
  int b = gid >> 8;
  int qs64 = qs * 64;
  int q0 = qs64 + wave * 16;

  const size_t qoff = (size_t)(b * S_ + q0 + lq) * QKV_ + h * HD_;
  short8 a0 = *(const short8*)&qkv[qoff + quad * 8];
  short8 a1 = *(const short8*)&qkv[qoff + 32 + quad * 8];

  f32x4 o[4] = {};
  float rs[4] = {0.f, 0.f, 0.f, 0.f};

  int start = qs64 - WIN_; if (start < 0) start = 0;
  int end = qs64 + 64 + WIN_; if (end > S_) end = S_;
  const int wlo = q0 - WIN_;
  const int whi = q0 + 16 + WIN_;

  const ushort_t* kg = qkv + (size_t)(b * S_) * QKV_ + 1024 + h * HD_;
  const ushort_t* vg = vt + (size_t)((b * H_ + h) * HD_) * S_;

  const int krow = lane >> 3;
  const int kchg = ((lane & 7) ^ krow) << 3;
  const int vrow = lane >> 2;
  const int vchg = ((lane & 3) ^ ((lane >> 3) & 3)) << 3;

  gld_lds16(kg + (size_t)(start + wave * 8 + krow) * QKV_ + kchg, &sK[0][wave * 512]);
  gld_lds16(vg + (size_t)(wave * 16 + vrow) * S_ + start + vchg, &sV[0][wave * 512]);

  const int nch = (end - start) >> 5;
  int buf = 0;
  for (int c = 0; c < nch; c++) {
    __syncthreads();
    int kb = start + c * 32;
    if (c + 1 < nch) {
      int nkb = kb + 32;
      gld_lds16(kg + (size_t)(nkb + wave * 8 + krow) * QKV_ + kchg, &sK[buf ^ 1][wave * 512]);
      gld_lds16(vg + (size_t)(wave * 16 + vrow) * S_ + nkb + vchg, &sV[buf ^ 1][wave * 512]);
    }
    if (kb < whi && kb + 32 > wlo) {
      f32x4 s[2];
#pragma unroll
      for (int t = 0; t < 2; t++) {
        const ushort_t* kr = &sK[buf][(t * 16 + lq) * 64];
        short8 b0 = *(const short8*)&kr[((quad ^ (lq & 7)) << 3)];
        short8 b1 = *(const short8*)&kr[(((4 + quad) ^ (lq & 7)) << 3)];
        f32x4 z = {};
        z = __builtin_amdgcn_mfma_f32_16x16x32_bf16(a0, b0, z, 0, 0, 0);
        z = __builtin_amdgcn_mfma_f32_16x16x32_bf16(a1, b1, z, 0, 0, 0);
        s[t] = z;
      }
      float p[2][4];
      const bool full = (kb >= q0 - 241) && (kb <= q0 + 225);
      if (full) {
#pragma unroll
        for (int t = 0; t < 2; t++)
#pragma unroll
          for (int r = 0; r < 4; r++) p[t][r] = fast_exp2(s[t][r] * SC_);
      } else {
#pragma unroll
        for (int t = 0; t < 2; t++) {
          int ki = kb + t * 16 + lq;
#pragma unroll
          for (int r = 0; r < 4; r++) {
            int dd = q0 + quad * 4 + r - ki;
            bool allowed = (dd <= WIN_) && (dd >= -WIN_);
            p[t][r] = allowed ? fast_exp2(s[t][r] * SC_) : 0.f;
          }
        }
      }
#pragma unroll
      for (int r = 0; r < 4; r++) rs[r] += p[0][r] + p[1][r];

#pragma unroll
      for (int t = 0; t < 2; t++)
#pragma unroll
        for (int r = 0; r < 4; r++)
          sP[wave][(quad * 4 + r) * 36 + t * 16 + lq] = f2b_trunc(p[t][r]);
      asm volatile("s_waitcnt lgkmcnt(0)" ::: "memory");
      short8 ap = *(const short8*)&sP[wave][lq * 36 + quad * 8];

#pragma unroll
      for (int nt = 0; nt < 4; nt++) {
        short8 bvf = *(const short8*)&sV[buf][(nt * 16 + lq) * 32 +
                                             ((quad ^ ((lq >> 1) & 3)) << 3)];
        o[nt] = __builtin_amdgcn_mfma_f32_16x16x32_bf16(ap, bvf, o[nt], 0, 0, 0);
      }
    }
    buf ^= 1;
  }

  float inv[4];
#pragma unroll
  for (int r = 0; r < 4; r++) {
    float v = rs[r];
    v += __shfl_xor(v, 1);
    v += __shfl_xor(v, 2);
    v += __shfl_xor(v, 4);
    v += __shfl_xor(v, 8);
    inv[r] = 1.f / v;
  }

#pragma unroll
  for (int nt = 0; nt < 4; nt++)
#pragma unroll
    for (int r = 0; r < 4; r++) {
      int row = q0 + quad * 4 + r;
      int col = h * HD_ + nt * 16 + lq;
      ctx[(size_t)(b * S_ + row) * E_ + col] = f2b(o[nt][r] * inv[r]);
    }
}

// ---------------------------------------------------------------------------
// y = A + Bv (residual, Bv bf16); out = LN(y)*g + b. outf fp32; outb bf16 opt.
// ---------------------------------------------------------------------------
__global__ __launch_bounds__(256) void ln_res_kernel(const float* __restrict__ A,
                                                     const ushort_t* __restrict__ Bv,
                                                     const float* __restrict__ g,
                                                     const float* __restrict__ be,
                                                     float* __restrict__ outf,
                                                     ushort_t* __restrict__ outb) {
  const int row = blockIdx.x;
  const int tid = threadIdx.x;
  const size_t base = (size_t)row * 1024;
  float4 a4 = ((const float4*)(A + base))[tid];
  us4 b4 = ((const us4*)(Bv + base))[tid];
  float v[4];
  v[0] = a4.x + b2f(b4.x);
  v[1] = a4.y + b2f(b4.y);
  v[2] = a4.z + b2f(b4.z);
  v[3] = a4.w + b2f(b4.w);
  float s = v[0] + v[1] + v[2] + v[3];
  float sq = v[0] * v[0] + v[1] * v[1] + v[2] * v[2] + v[3] * v[3];
#pragma unroll
  for (int off = 32; off; off >>= 1) {
    s += __shfl_xor(s, off);
    sq += __shfl_xor(sq, off);
  }
  __shared__ float ls[4], lsq[4];
  int wave = tid >> 6, lane = tid & 63;
  if (lane == 0) { ls[wave] = s; lsq[wave] = sq; }
  __syncthreads();
  s = ls[0] + ls[1] + ls[2] + ls[3];
  sq = lsq[0] + lsq[1] + lsq[2] + lsq[3];
  float mean = s * (1.f / 1024.f);
  float var = sq * (1.f / 1024.f) - mean * mean;
  float rstd = rsqrtf(var + 1e-5f);
  float4 g4 = ((const float4*)g)[tid];
  float4 e4 = ((const float4*)be)[tid];
  float o0 = (v[0] - mean) * rstd * g4.x + e4.x;
  float o1 = (v[1] - mean) * rstd * g4.y + e4.y;
  float o2 = (v[2] - mean) * rstd * g4.z + e4.z;
  float o3 = (v[3] - mean) * rstd * g4.w + e4.w;
  float4 of = {o0, o1, o2, o3};
  ((float4*)(outf + base))[tid] = of;
  if (outb) {
    us4 ob;
    ob.x = f2b(o0); ob.y = f2b(o1); ob.z = f2b(o2); ob.w = f2b(o3);
    ((us4*)(outb + base))[tid] = ob;
  }
}

// ---------------------------------------------------------------------------
// Split-K fused LN2: y = x1 + P0 + P1 + bias (all fp32); out = LN(y)*g + b.
// ---------------------------------------------------------------------------
__global__ __launch_bounds__(256) void ln_res2_kernel(const float* __restrict__ A,
                                                      const float* __restrict__ P0,
                                                      const float* __restrict__ P1,
                                                      const float* __restrict__ bias,
                                                      const float* __restrict__ g,
                                                      const float* __restrict__ be,
                                                      float* __restrict__ outf) {
  const int row = blockIdx.x;
  const int tid = threadIdx.x;
  const size_t base = (size_t)row * 1024;
  float4 a4 = ((const float4*)(A + base))[tid];
  float4 p04 = ((const float4*)(P0 + base))[tid];
  float4 p14 = ((const float4*)(P1 + base))[tid];
  float4 bi4 = ((const float4*)bias)[tid];
  float v[4];
  v[0] = a4.x + p04.x + p14.x + bi4.x;
  v[1] = a4.y + p04.y + p14.y + bi4.y;
  v[2] = a4.z + p04.z + p14.z + bi4.z;
  v[3] = a4.w + p04.w + p14.w + bi4.w;
  float s = v[0] + v[1] + v[2] + v[3];
  float sq = v[0] * v[0] + v[1] * v[1] + v[2] * v[2] + v[3] * v[3];
#pragma unroll
  for (int off = 32; off; off >>= 1) {
    s += __shfl_xor(s, off);
    sq += __shfl_xor(sq, off);
  }
  __shared__ float ls[4], lsq[4];
  int wave = tid >> 6, lane = tid & 63;
  if (lane == 0) { ls[wave] = s; lsq[wave] = sq; }
  __syncthreads();
  s = ls[0] + ls[1] + ls[2] + ls[3];
  sq = lsq[0] + lsq[1] + lsq[2] + lsq[3];
  float mean = s * (1.f / 1024.f);
  float var = sq * (1.f / 1024.f) - mean * mean;
  float rstd = rsqrtf(var + 1e-5f);
  float4 g4 = ((const float4*)g)[tid];
  float4 e4 = ((const float4*)be)[tid];
  float4 of;
  of.x = (v[0] - mean) * rstd * g4.x + e4.x;
  of.y = (v[1] - mean) * rstd * g4.y + e4.y;
  of.z = (v[2] - mean) * rstd * g4.z + e4.z;
  of.w = (v[3] - mean) * rstd * g4.w + e4.w;
  ((float4*)(outf + base))[tid] = of;
}

// ---------------------------------------------------------------------------
// Workspace layout (bytes), lifetime-overlapped. Budget 200 MiB.
// ---------------------------------------------------------------------------
#define O_XBF   ((size_t)0)            // x bf16; later x1 bf16; later P0 (32MB w/ roped)
#define O_ROPED ((size_t)16777216)     // roped bf16; later ctx bf16; later P0 tail
#define O_W_IN  ((size_t)33554432)     // in_proj_w bf16 [3072][1024]
#define O_W_OUT ((size_t)39845888)     // out_proj_w bf16 [1024][1024]
#define O_W1    ((size_t)41943040)     // w1 bf16 [4096][1024]
#define O_W2    ((size_t)50331648)     // w2 bf16 [1024][4096]
#define O_BIG   ((size_t)58720256)     // qkv bf16 [8192][3072]; then h; then ff1
#define O_VT    ((size_t)125829120)    // V^T bf16 [B,H,HD,S]
#define O_X1F   ((size_t)142606336)    // x1 fp32 [8192][1024]
#define O_P1    ((size_t)176160768)    // FF2 partial 1 fp32 [8192][1024] (ends at 200 MiB)

extern "C" void kernel_launch(void* const* d_in, const int* in_sizes, int n_in,
                              void* d_out, int out_size, void* d_ws, size_t ws_size,
                              hipStream_t stream) {
  const float* x          = (const float*)d_in[0];
  const float* in_proj_w  = (const float*)d_in[1];
  const float* in_proj_b  = (const float*)d_in[2];
  const float* out_proj_w = (const float*)d_in[3];
  const float* out_proj_b = (const float*)d_in[4];
  const float* ln1_g      = (const float*)d_in[5];
  const float* ln1_b      = (const float*)d_in[6];
  const float* w1         = (const float*)d_in[7];
  const float* b1         = (const float*)d_in[8];
  const float* w2         = (const float*)d_in[9];
  const float* b2         = (const float*)d_in[10];
  const float* ln2_g      = (const float*)d_in[11];
  const float* ln2_b      = (const float*)d_in[12];
  float* out = (float*)d_out;

  char* ws = (char*)d_ws;
  ushort_t* xbf     = (ushort_t*)(ws + O_XBF);
  ushort_t* roped   = (ushort_t*)(ws + O_ROPED);
  ushort_t* wbf_in  = (ushort_t*)(ws + O_W_IN);
  ushort_t* wbf_out = (ushort_t*)(ws + O_W_OUT);
  ushort_t* wbf_1   = (ushort_t*)(ws + O_W1);
  ushort_t* wbf_2   = (ushort_t*)(ws + O_W2);
  ushort_t* qkv_buf = (ushort_t*)(ws + O_BIG);
  ushort_t* vtb     = (ushort_t*)(ws + O_VT);
  ushort_t* ctx     = (ushort_t*)(ws + O_ROPED);  // reuse roped
  ushort_t* h_bf    = (ushort_t*)(ws + O_BIG);    // reuse qkv region
  float*    x1f     = (float*)(ws + O_X1F);
  ushort_t* x1bf    = (ushort_t*)(ws + O_XBF);    // reuse xbf
  ushort_t* ff1     = (ushort_t*)(ws + O_BIG);    // reuse h region
  float*    p0      = (float*)(ws + O_XBF);       // FF2 partial 0: [0,32MB)
  float*    p1      = (float*)(ws + O_P1);        // FF2 partial 1

  dim3 blk(256);
  dim3 blk512(512);
  const int NOSPLIT = 1 << 30;

  // 1) weight casts to bf16 (single launch)
  cast4_kernel<<<dim3(12288), blk, 0, stream>>>(in_proj_w, out_proj_w, w1, w2,
                                                wbf_in, wbf_out, wbf_1, wbf_2);

  // 2) RoPE (+ x cast)
  rope_kernel<<<dim3(16384), blk, 0, stream>>>(x, roped, xbf);

  // 3) QKV merged: cols 0..2047 use roped, cols 2048.. use xbf (N=3072).
  //    Grid 384 = 8 chunks of 8bx x 6by (per-XCD ~7 MiB working set).
  gemm256<0><<<dim3(384), blk512, 0, stream>>>(roped, xbf, 2048, wbf_in, in_proj_b,
                                               qkv_buf, QKV_, 1024, 1024, 32, 12, 8, 6);
  // 4) V transpose -> [B,H,HD,S]
  vtrans_kernel<<<dim3(2048), blk, 0, stream>>>(qkv_buf, vtb);

  // 5) windowed flash attention -> ctx bf16
  attn_kernel<<<dim3(2048), blk, 0, stream>>>(qkv_buf, vtb, ctx);

  // 6) h = ctx @ Wo^T + bo (bf16 out; N=1024 K=1024 -> 128^2 kernel)
  gemm_bt<0><<<dim3(64, 8), blk, 0, stream>>>(ctx, ctx, NOSPLIT, wbf_out, out_proj_b,
                                              h_bf, 1024, 1024);

  // 7) x1 = LN1(x + h) -> fp32 + bf16
  ln_res_kernel<<<dim3(8192), blk, 0, stream>>>(x, h_bf, ln1_g, ln1_b, x1f, x1bf);

  // 8) ff1 = gelu(x1 @ W1^T + b1) bf16 (N=4096).
  //    Grid 512 = 8 chunks of 8bx x 8by (per-XCD ~8 MiB vs 17 before).
  gemm256<1><<<dim3(512), blk512, 0, stream>>>(x1bf, x1bf, NOSPLIT, wbf_1, b1,
                                               ff1, 4096, 1024, 1024, 32, 16, 8, 8);

  // 9) FF2 split-K=2 -> fp32 partials p0 (ks=0) / p1 (ks=1, via 'bias' slot).
  //    Grid 256 = 8 chunks of 8bx x 4byt (per-XCD ~12 MiB vs 33 before).
  gemm256<2><<<dim3(256), blk512, 0, stream>>>(ff1, ff1, NOSPLIT, wbf_2,
                                               (const float*)p1, (ushort_t*)p0,
                                               1024, 2048, 4096, 32, 4, 8, 4);

  // 10) out = LN2(x1 + p0 + p1 + b2)
  ln_res2_kernel<<<dim3(8192), blk, 0, stream>>>(x1f, p0, p1, b2, ln2_g, ln2_b, out);
}